// Round 3
// baseline (467.847 us; speedup 1.0000x reference)
//
#include <hip/hip_runtime.h>

#define NB 8
#define NT 30000
#define NL 6
#define NC 32
#define NHID 256

typedef _Float16 f16;
typedef f16 half8 __attribute__((ext_vector_type(8)));
typedef f16 half4v __attribute__((ext_vector_type(4)));
typedef f16 half2v __attribute__((ext_vector_type(2)));
typedef float floatx4 __attribute__((ext_vector_type(4)));

// Row permutation so MFMA D-layout lands in "lane(q) owns channels 8q..8q+7" order.
__device__ __forceinline__ int permrow(int m) {
    return 8 * ((m & 15) >> 2) + 4 * (m >> 4) + (m & 3);
}

__device__ __forceinline__ half2v cvt2(float a, float b) {
    auto t = __builtin_amdgcn_cvt_pkrtz(a, b);
    return *(half2v*)&t;
}

__device__ __forceinline__ half8 relupack(const float in[8]) {
    union { half8 v; half2v p[4]; } u;
    u.p[0] = cvt2(fmaxf(in[0], 0.f), fmaxf(in[1], 0.f));
    u.p[1] = cvt2(fmaxf(in[2], 0.f), fmaxf(in[3], 0.f));
    u.p[2] = cvt2(fmaxf(in[4], 0.f), fmaxf(in[5], 0.f));
    u.p[3] = cvt2(fmaxf(in[6], 0.f), fmaxf(in[7], 0.f));
    return u.v;
}

// Parallel fold: M = blk0_ws @ fc_p_w (32x3), v = blk0_ws @ fc_p_b. 256 threads.
__global__ void fold_kernel(const float* __restrict__ ws, const float* __restrict__ fpw,
                            const float* __restrict__ fpb, floatx4* __restrict__ out) {
    __shared__ floatx4 s_part[8][32];
    int tid = threadIdx.x;
    int i = tid & 31, kc = tid >> 5;
    const float* wrow = ws + i * 256 + kc * 32;
    const float* pw = fpw + kc * 96;
    const float* pb = fpb + kc * 32;
    floatx4 acc = {};
    #pragma unroll 8
    for (int k = 0; k < 32; k++) {
        float w = wrow[k];
        acc[0] = fmaf(w, pw[k * 3 + 0], acc[0]);
        acc[1] = fmaf(w, pw[k * 3 + 1], acc[1]);
        acc[2] = fmaf(w, pw[k * 3 + 2], acc[2]);
        acc[3] = fmaf(w, pb[k], acc[3]);
    }
    s_part[kc][i] = acc;
    __syncthreads();
    if (kc == 0) {
        floatx4 s = s_part[0][i];
        #pragma unroll
        for (int j = 1; j < 8; j++) s += s_part[j][i];
        out[i] = s;
    }
}

// One 32x32 GEMM step; soff0/soff1 are swizzled f16 offsets for rows i16 / 16+i16.
__device__ __forceinline__ void gemm32(const f16* __restrict__ wmat, int soff0, int soff1,
                                       const float in[8], floatx4& o0, floatx4& o1) {
    half8 bf = relupack(in);
    half8 a0 = *(const half8*)(wmat + soff0);
    half8 a1 = *(const half8*)(wmat + soff1);
    o0 = __builtin_amdgcn_mfma_f32_16x16x32_f16(a0, bf, o0, 0, 0, 0);
    o1 = __builtin_amdgcn_mfma_f32_16x16x32_f16(a1, bf, o1, 0, 0, 0);
}

__launch_bounds__(256, 4)
__global__ void decoder_kernel(
    const float* __restrict__ p, const float* __restrict__ c, const float* __restrict__ Cm,
    const float* __restrict__ fpw, const float* __restrict__ fpb,
    const float* __restrict__ b0w0, const float* __restrict__ b0b0,
    const float* __restrict__ b0w1, const float* __restrict__ b0b1,
    const float* __restrict__ bw0, const float* __restrict__ bb0,
    const float* __restrict__ bw1, const float* __restrict__ bb1,
    const float* __restrict__ fow, const float* __restrict__ fob,
    const floatx4* __restrict__ fold, float* __restrict__ out)
{
    // XOR-swizzled (16B-chunk) layouts, no pads:
    __shared__ __align__(16) f16 s_w0A[32 * 256];   // 16 KB   chunk c -> c ^ (m&7)
    __shared__ __align__(16) f16 s_wA[9 * 32 * 32]; // 18 KB   chunk c -> c ^ ((m>>1)&3)
    __shared__ __align__(16) f16 s_hA[256 * 4];     // 2 KB    {w0,w1,w2,b} per permuted hidden
    __shared__ floatx4 s_fold[36];
    __shared__ __align__(16) float s_b0b0[32], s_b0b1[32], s_fow[32];
    __shared__ __align__(16) float s_bb0f[128], s_bb1f[128];
    __shared__ float s_cam[NL][8];
    __shared__ float s_fob;

    const int tid = threadIdx.x;
    const int b = blockIdx.y;

    // ---- staging (vectorized, row-structured) ----
    {   // s_w0A: thread -> row m = tid>>3, segment seg = tid&7 (4 chunks of 8 f16)
        int m = tid >> 3, seg = tid & 7;
        const float* src = b0w0 + permrow(m) * 256 + seg * 32;
        f16* dst = s_w0A + m * 256;
        int sw = m & 7;
        #pragma unroll
        for (int ci = 0; ci < 4; ci++) {
            int cidx = seg * 4 + ci;
            floatx4 f0 = *(const floatx4*)(src + ci * 8);
            floatx4 f1 = *(const floatx4*)(src + ci * 8 + 4);
            half8 h;
            #pragma unroll
            for (int j = 0; j < 4; j++) { h[j] = (f16)f0[j]; h[4 + j] = (f16)f1[j]; }
            *(half8*)(dst + ((cidx ^ sw) << 3)) = h;
        }
    }
    // s_wA: 288 rows; thread handles row tid (+ row tid+256 if tid<32)
    for (int r = tid; r < 288; r += 256) {
        int mi = r >> 5, m = r & 31;
        int pm = permrow(m);
        const float* src;
        if (mi == 0) src = b0w1 + pm * 32;
        else {
            int mat = mi - 1, bi = mat >> 1;
            src = ((mat & 1) ? bw1 : bw0) + (bi * 32 + pm) * 32;
        }
        f16* dst = s_wA + mi * 1024 + m * 32;
        int sw = (m >> 1) & 3;
        #pragma unroll
        for (int ci = 0; ci < 4; ci++) {
            floatx4 f0 = *(const floatx4*)(src + ci * 8);
            floatx4 f1 = *(const floatx4*)(src + ci * 8 + 4);
            half8 h;
            #pragma unroll
            for (int j = 0; j < 4; j++) { h[j] = (f16)f0[j]; h[4 + j] = (f16)f1[j]; }
            *(half8*)(dst + ((ci ^ sw) << 3)) = h;
        }
    }
    {   // s_hA: row tid holds {fpw[h], fpb[h]} with h = chunk*32 + permrow(m)
        int cch = tid >> 5, m = tid & 31;
        int h = cch * 32 + permrow(m);
        half4v v;
        v[0] = (f16)fpw[h * 3 + 0]; v[1] = (f16)fpw[h * 3 + 1];
        v[2] = (f16)fpw[h * 3 + 2]; v[3] = (f16)fpb[h];
        *(half4v*)(s_hA + tid * 4) = v;
    }
    if (tid < 32) {
        s_b0b0[tid] = b0b0[tid];
        s_b0b1[tid] = b0b1[tid];
        s_fow[tid]  = fow[tid];
        s_fold[tid + (tid >> 3)] = fold[tid];
    }
    if (tid >= 64 && tid < 192) {
        int j = tid - 64;
        s_bb0f[j] = bb0[j];
        s_bb1f[j] = bb1[j];
    }
    if (tid == 0) s_fob = fob[0];
    if (tid >= 192 && tid < 192 + NL) {
        int l = tid - 192;
        const float* cm = Cm + ((size_t)b * NL + l) * 12;
        float denom = cm[9] + 0.05f;
        float s = 63.5f / (0.55f * denom);
        s_cam[l][0] = cm[0] * s; s_cam[l][1] = cm[1] * s; s_cam[l][2] = cm[2] * s;
        s_cam[l][3] = cm[3] * s; s_cam[l][4] = cm[4] * s; s_cam[l][5] = cm[5] * s;
    }
    __syncthreads();

    const int lane = tid & 63;
    const int wv = tid >> 6;
    const int q = lane >> 4;
    const int i16 = lane & 15;

    // Precomputed swizzled LDS offsets (group-invariant)
    const int sw0 = i16 & 7;
    const f16* w0r0 = s_w0A + i16 * 256;
    const f16* w0r1 = s_w0A + (16 + i16) * 256;
    const int qsw = (q ^ ((i16 >> 1) & 3)) << 3;
    const int soff0 = i16 * 32 + qsw;
    const int soff1 = (16 + i16) * 32 + qsw;
    const f16* hr0 = s_hA + i16 * 4;
    const f16* hr1 = s_hA + (16 + i16) * 4;
    const float* cq = c + (((size_t)b * NL) << 19) + q * 8;

    #pragma unroll 1
    for (int g = 0; g < 4; g++) {
        const int t = blockIdx.x * 256 + (g * 4 + wv) * 16 + i16;
        const int tc = min(t, NT - 1);
        const float* pp = p + ((size_t)b * NT + tc) * 3;
        float px = pp[0], py = pp[1], pz = pp[2];

        // ---- bilinear multi-view gather (lane: its 8 channels) ----
        floatx4 fe0 = {}, fe1 = {};
        #pragma unroll 2
        for (int l = 0; l < NL; l++) {
            float x = s_cam[l][0] * px + s_cam[l][1] * py + s_cam[l][2] * pz + 63.5f;
            float y = s_cam[l][3] * px + s_cam[l][4] * py + s_cam[l][5] * pz + 63.5f;
            float x0f = floorf(x), x1f = ceilf(x);
            float y0f = floorf(y), y1f = ceilf(y);
            float dxw = x1f - x, dyw = y1f - y;
            int x0 = min(max((int)x0f, 0), 127);
            int x1 = min(max((int)x1f, 0), 127);
            int y0 = min(max((int)y0f, 0), 127);
            int y1 = min(max((int)y1f, 0), 127);
            const float* base = cq + ((size_t)l << 19);
            const floatx4* f11 = (const floatx4*)(base + (size_t)((x0 << 7) + y0) * 32);
            const floatx4* f12 = (const floatx4*)(base + (size_t)((x1 << 7) + y0) * 32);
            const floatx4* f21 = (const floatx4*)(base + (size_t)((x0 << 7) + y1) * 32);
            const floatx4* f22 = (const floatx4*)(base + (size_t)((x1 << 7) + y1) * 32);
            float w11 = dxw * dyw;
            float w12 = (1.f - dxw) * dyw;
            float w21 = dxw * (1.f - dyw);
            float w22 = (1.f - dxw) * (1.f - dyw);
            floatx4 a0 = f11[0], a1 = f11[1];
            floatx4 b0v = f12[0], b1v = f12[1];
            floatx4 c0 = f21[0], c1 = f21[1];
            floatx4 d0 = f22[0], d1 = f22[1];
            fe0 += a0 * w11 + b0v * w12 + c0 * w21 + d0 * w22;
            fe1 += a1 * w11 + b1v * w12 + c1 * w21 + d1 * w22;
        }
        float feat[8];
        #pragma unroll
        for (int r = 0; r < 4; r++) { feat[r] = fe0[r]; feat[4 + r] = fe1[r]; }

        // ---- blk0: hidden layer via MFMA (B = (px,py,pz,1) on quad 0 only) ----
        half8 bp;
        {
            union { half8 v; half2v p2[4]; } u;
            half2v z = {};
            u.p2[0] = (q == 0) ? cvt2(px, py) : z;
            u.p2[1] = (q == 0) ? cvt2(pz, 1.0f) : z;
            u.p2[2] = z; u.p2[3] = z;
            bp = u.v;
        }
        floatx4 acc0 = *(const floatx4*)&s_b0b0[q * 8];
        floatx4 acc1 = *(const floatx4*)&s_b0b0[q * 8 + 4];
        #pragma unroll
        for (int cch = 0; cch < 8; cch++) {
            half4v lo = *(const half4v*)(hr0 + cch * 128);
            half4v hi = *(const half4v*)(hr1 + cch * 128);
            half8 alo, ahi;
            #pragma unroll
            for (int j = 0; j < 4; j++) {
                alo[j] = lo[j]; alo[4 + j] = lo[j];
                ahi[j] = hi[j]; ahi[4 + j] = hi[j];
            }
            floatx4 hz = {};
            floatx4 h0 = __builtin_amdgcn_mfma_f32_16x16x32_f16(alo, bp, hz, 0, 0, 0);
            floatx4 h1 = __builtin_amdgcn_mfma_f32_16x16x32_f16(ahi, bp, hz, 0, 0, 0);
            float hv[8];
            #pragma unroll
            for (int r = 0; r < 4; r++) { hv[r] = h0[r]; hv[4 + r] = h1[r]; }
            half8 bf = relupack(hv);
            half8 a0 = *(const half8*)(w0r0 + ((((cch << 2) | q) ^ sw0) << 3));
            half8 a1 = *(const half8*)(w0r1 + ((((cch << 2) | q) ^ sw0) << 3));
            acc0 = __builtin_amdgcn_mfma_f32_16x16x32_f16(a0, bf, acc0, 0, 0, 0);
            acc1 = __builtin_amdgcn_mfma_f32_16x16x32_f16(a1, bf, acc1, 0, 0, 0);
        }

        // ---- blk0 second layer + folded shortcut + feat ----
        float hbuf[8];
        #pragma unroll
        for (int r = 0; r < 4; r++) { hbuf[r] = acc0[r]; hbuf[4 + r] = acc1[r]; }
        floatx4 n0 = *(const floatx4*)&s_b0b1[q * 8];
        floatx4 n1 = *(const floatx4*)&s_b0b1[q * 8 + 4];
        gemm32(s_wA, soff0, soff1, hbuf, n0, n1);

        float st[8];
        #pragma unroll
        for (int j = 0; j < 8; j++) {
            floatx4 f = s_fold[q * 9 + j];
            float sc = f[0] * px + f[1] * py + f[2] * pz + f[3];
            st[j] = ((j < 4) ? n0[j] : n1[j - 4]) + sc + feat[j];
        }

        // ---- residual blocks ----
        #pragma unroll
        for (int bk = 0; bk < 4; bk++) {
            floatx4 h0 = *(const floatx4*)&s_bb0f[bk * 32 + q * 8];
            floatx4 h1 = *(const floatx4*)&s_bb0f[bk * 32 + q * 8 + 4];
            gemm32(s_wA + (1 + 2 * bk) * 1024, soff0, soff1, st, h0, h1);
            float hb[8];
            #pragma unroll
            for (int r = 0; r < 4; r++) { hb[r] = h0[r]; hb[4 + r] = h1[r]; }
            floatx4 d0 = *(const floatx4*)&s_bb1f[bk * 32 + q * 8];
            floatx4 d1 = *(const floatx4*)&s_bb1f[bk * 32 + q * 8 + 4];
            gemm32(s_wA + (2 + 2 * bk) * 1024, soff0, soff1, hb, d0, d1);
            #pragma unroll
            for (int j = 0; j < 8; j++)
                st[j] += ((j < 4) ? d0[j] : d1[j - 4]) + feat[j];
        }

        // ---- head ----
        floatx4 fw0 = *(const floatx4*)&s_fow[q * 8];
        floatx4 fw1 = *(const floatx4*)&s_fow[q * 8 + 4];
        float o = 0.f;
        #pragma unroll
        for (int r = 0; r < 4; r++)
            o += fmaxf(st[r], 0.f) * fw0[r] + fmaxf(st[4 + r], 0.f) * fw1[r];
        o += __shfl_xor(o, 16);
        o += __shfl_xor(o, 32);
        if (q == 0 && t < NT) out[(size_t)b * NT + t] = o + s_fob;
    }
}

extern "C" void kernel_launch(void* const* d_in, const int* in_sizes, int n_in,
                              void* d_out, int out_size, void* d_ws, size_t ws_size,
                              hipStream_t stream) {
    const float* p    = (const float*)d_in[0];
    const float* c    = (const float*)d_in[2];
    const float* Cm   = (const float*)d_in[3];
    const float* fpw  = (const float*)d_in[4];
    const float* fpb  = (const float*)d_in[5];
    const float* b0w0 = (const float*)d_in[6];
    const float* b0b0 = (const float*)d_in[7];
    const float* b0w1 = (const float*)d_in[8];
    const float* b0b1 = (const float*)d_in[9];
    const float* b0ws = (const float*)d_in[10];
    const float* bw0  = (const float*)d_in[11];
    const float* bb0  = (const float*)d_in[12];
    const float* bw1  = (const float*)d_in[13];
    const float* bb1  = (const float*)d_in[14];
    const float* fow  = (const float*)d_in[15];
    const float* fob  = (const float*)d_in[16];
    floatx4* fold = (floatx4*)d_ws;

    fold_kernel<<<1, 256, 0, stream>>>(b0ws, fpw, fpb, fold);

    dim3 grid((NT + 255) / 256, NB);
    decoder_kernel<<<grid, 256, 0, stream>>>(p, c, Cm, fpw, fpb,
                                             b0w0, b0b0, b0w1, b0b1,
                                             bw0, bb0, bw1, bb1,
                                             fow, fob, fold, (float*)d_out);
}

// Round 4
// 401.414 us; speedup vs baseline: 1.1655x; 1.1655x over previous
//
#include <hip/hip_runtime.h>

#define NB 8
#define NT 30000
#define NL 6
#define NC 32
#define NHID 256

typedef _Float16 f16;
typedef f16 half8 __attribute__((ext_vector_type(8)));
typedef f16 half4v __attribute__((ext_vector_type(4)));
typedef f16 half2v __attribute__((ext_vector_type(2)));
typedef float floatx4 __attribute__((ext_vector_type(4)));

// Row permutation so MFMA D-layout lands in "lane(q) owns channels 8q..8q+7" order.
__device__ __forceinline__ int permrow(int m) {
    return 8 * ((m & 15) >> 2) + 4 * (m >> 4) + (m & 3);
}

__device__ __forceinline__ half2v cvt2(float a, float b) {
    auto t = __builtin_amdgcn_cvt_pkrtz(a, b);
    return *(half2v*)&t;
}

__device__ __forceinline__ half8 relupack2(floatx4 a, floatx4 b) {
    union { half8 v; half2v p[4]; } u;
    u.p[0] = cvt2(fmaxf(a[0], 0.f), fmaxf(a[1], 0.f));
    u.p[1] = cvt2(fmaxf(a[2], 0.f), fmaxf(a[3], 0.f));
    u.p[2] = cvt2(fmaxf(b[0], 0.f), fmaxf(b[1], 0.f));
    u.p[3] = cvt2(fmaxf(b[2], 0.f), fmaxf(b[3], 0.f));
    return u.v;
}

// Parallel fold: M = blk0_ws @ fc_p_w (32x3), v = blk0_ws @ fc_p_b. 256 threads.
__global__ void fold_kernel(const float* __restrict__ ws, const float* __restrict__ fpw,
                            const float* __restrict__ fpb, floatx4* __restrict__ out) {
    __shared__ floatx4 s_part[8][32];
    int tid = threadIdx.x;
    int i = tid & 31, kc = tid >> 5;
    const float* wrow = ws + i * 256 + kc * 32;
    const float* pw = fpw + kc * 96;
    const float* pb = fpb + kc * 32;
    floatx4 acc = {};
    #pragma unroll 8
    for (int k = 0; k < 32; k++) {
        float w = wrow[k];
        acc[0] = fmaf(w, pw[k * 3 + 0], acc[0]);
        acc[1] = fmaf(w, pw[k * 3 + 1], acc[1]);
        acc[2] = fmaf(w, pw[k * 3 + 2], acc[2]);
        acc[3] = fmaf(w, pb[k], acc[3]);
    }
    s_part[kc][i] = acc;
    __syncthreads();
    if (kc == 0) {
        floatx4 s = s_part[0][i];
        #pragma unroll
        for (int j = 1; j < 8; j++) s += s_part[j][i];
        out[i] = s;
    }
}

__launch_bounds__(256, 3)
__global__ void decoder_kernel(
    const float* __restrict__ p, const float* __restrict__ c, const float* __restrict__ Cm,
    const float* __restrict__ fpw, const float* __restrict__ fpb,
    const float* __restrict__ b0w0, const float* __restrict__ b0b0,
    const float* __restrict__ b0w1, const float* __restrict__ b0b1,
    const float* __restrict__ bw0, const float* __restrict__ bb0,
    const float* __restrict__ bw1, const float* __restrict__ bb1,
    const float* __restrict__ fow, const float* __restrict__ fob,
    const floatx4* __restrict__ fold, float* __restrict__ out)
{
    __shared__ __align__(16) f16 s_w0A[32 * 256];   // 16 KB; b128 chunk c -> c ^ (m&7)
    __shared__ __align__(16) f16 s_wA[9 * 32 * 32]; // 18 KB; b64 chunk c -> c ^ (m&7)
    __shared__ __align__(16) f16 s_hB[256 * 4];     // 2 KB; hidden {w0,w1,w2,b} rows
    __shared__ __align__(16) f16 s_foldA[32 * 4];   // 256 B; {M0,M1,M2,v+b0b1}
    __shared__ __align__(16) float s_b0b0[32], s_fow[32];
    __shared__ __align__(16) float s_bb0f[128], s_bb1f[128];
    __shared__ float s_cam[NL][8];
    __shared__ float s_fob;

    const int tid = threadIdx.x;
    const int b = blockIdx.y;

    // ---- staging ----
    {   // s_w0A: row m = tid>>3, seg = tid&7 -> 4 b128 chunks, slot = chunk ^ (m&7)
        int m = tid >> 3, seg = tid & 7;
        const float* src = b0w0 + permrow(m) * 256 + seg * 32;
        f16* dst = s_w0A + m * 256;
        int sw = m & 7;
        #pragma unroll
        for (int ci = 0; ci < 4; ci++) {
            int cidx = seg * 4 + ci;
            floatx4 f0 = *(const floatx4*)(src + ci * 8);
            floatx4 f1 = *(const floatx4*)(src + ci * 8 + 4);
            half8 h;
            #pragma unroll
            for (int j = 0; j < 4; j++) { h[j] = (f16)f0[j]; h[4 + j] = (f16)f1[j]; }
            *(half8*)(dst + ((cidx ^ sw) << 3)) = h;
        }
    }
    // s_wA: 9 mats x 32 rows; b64 chunks c(0..7) at slot c ^ (m&7)
    for (int r = tid; r < 288; r += 256) {
        int mi = r >> 5, m = r & 31;
        int pm = permrow(m);
        const float* src;
        if (mi == 0) src = b0w1 + pm * 32;
        else {
            int mat = mi - 1, bi = mat >> 1;
            src = ((mat & 1) ? bw1 : bw0) + (bi * 32 + pm) * 32;
        }
        f16* dst = s_wA + mi * 1024 + m * 32;
        int sw = m & 7;
        #pragma unroll
        for (int ci = 0; ci < 8; ci++) {
            floatx4 f = *(const floatx4*)(src + ci * 4);
            half4v h = {(f16)f[0], (f16)f[1], (f16)f[2], (f16)f[3]};
            *(half4v*)(dst + ((ci ^ sw) << 2)) = h;
        }
    }
    {   // s_hB: row tid = (cch,m) holds hidden h = cch*32 + permrow(m)
        int cch = tid >> 5, m = tid & 31;
        int h = cch * 32 + permrow(m);
        half4v v = {(f16)fpw[h * 3 + 0], (f16)fpw[h * 3 + 1],
                    (f16)fpw[h * 3 + 2], (f16)fpb[h]};
        *(half4v*)(s_hB + tid * 4) = v;
    }
    if (tid < 32) {
        int pm = permrow(tid);
        floatx4 f = fold[pm];
        half4v v = {(f16)f[0], (f16)f[1], (f16)f[2], (f16)(f[3] + b0b1[pm])};
        *(half4v*)(s_foldA + tid * 4) = v;
        s_b0b0[tid] = b0b0[tid];
        s_fow[tid]  = fow[tid];
    }
    if (tid >= 64 && tid < 192) {
        int j = tid - 64;
        s_bb0f[j] = bb0[j];
        s_bb1f[j] = bb1[j];
    }
    if (tid == 0) s_fob = fob[0];
    if (tid >= 192 && tid < 192 + NL) {
        int l = tid - 192;
        const float* cm = Cm + ((size_t)b * NL + l) * 12;
        float denom = cm[9] + 0.05f;
        float s = 63.5f / (0.55f * denom);
        s_cam[l][0] = cm[0] * s; s_cam[l][1] = cm[1] * s; s_cam[l][2] = cm[2] * s;
        s_cam[l][3] = cm[3] * s; s_cam[l][4] = cm[4] * s; s_cam[l][5] = cm[5] * s;
    }
    __syncthreads();

    const int lane = tid & 63;
    const int wv = tid >> 6;
    const int q = lane >> 4;
    const int i16 = lane & 15;
    const int sw0 = i16 & 7;

    // group-invariant LDS bases/offsets
    const f16* w0r0 = s_w0A + i16 * 256;
    const f16* w0r1 = s_w0A + (16 + i16) * 256;
    const int rA = i16 * 32, rB = (16 + i16) * 32;           // s_wA row offsets (f16)
    const int c0 = ((2 * q) ^ sw0) << 2;                     // s_wA chunk slots
    const int c1 = ((2 * q + 1) ^ sw0) << 2;
    const f16* hB0 = s_hB + i16 * 4;
    const f16* hB1 = s_hB + (16 + i16) * 4;
    const float* cq = c + (((size_t)b * NL) << 19) + q * 8;

    // fold A-frags (g-invariant), hi halves zero (B rows 4..31 are exactly 0)
    const half4v zh4 = {};
    union uA { half8 v; half4v h[2]; };
    uA fA0, fA1;
    fA0.h[0] = *(const half4v*)(s_foldA + i16 * 4);        fA0.h[1] = zh4;
    fA1.h[0] = *(const half4v*)(s_foldA + (16 + i16) * 4); fA1.h[1] = zh4;
    const floatx4 fw0 = *(const floatx4*)&s_fow[q * 8];
    const floatx4 fw1 = *(const floatx4*)&s_fow[q * 8 + 4];
    const floatx4 b00a = *(const floatx4*)&s_b0b0[q * 8];
    const floatx4 b00b = *(const floatx4*)&s_b0b0[q * 8 + 4];

    #pragma unroll 1
    for (int g = 0; g < 2; g++) {
        const int t = blockIdx.x * 128 + (g * 4 + wv) * 16 + i16;
        const int tc = min(t, NT - 1);
        const float* pp = p + ((size_t)b * NT + tc) * 3;
        float px = pp[0], py = pp[1], pz = pp[2];

        // ---- bilinear multi-view gather (lane: its 8 channels) ----
        floatx4 fe0 = {}, fe1 = {};
        #pragma unroll 1
        for (int l = 0; l < NL; l++) {
            float x = s_cam[l][0] * px + s_cam[l][1] * py + s_cam[l][2] * pz + 63.5f;
            float y = s_cam[l][3] * px + s_cam[l][4] * py + s_cam[l][5] * pz + 63.5f;
            float x0f = floorf(x), x1f = ceilf(x);
            float y0f = floorf(y), y1f = ceilf(y);
            float dxw = x1f - x, dyw = y1f - y;
            int x0 = min(max((int)x0f, 0), 127);
            int x1 = min(max((int)x1f, 0), 127);
            int y0 = min(max((int)y0f, 0), 127);
            int y1 = min(max((int)y1f, 0), 127);
            const float* base = cq + ((size_t)l << 19);
            const floatx4* f11 = (const floatx4*)(base + (size_t)((x0 << 7) + y0) * 32);
            const floatx4* f12 = (const floatx4*)(base + (size_t)((x1 << 7) + y0) * 32);
            const floatx4* f21 = (const floatx4*)(base + (size_t)((x0 << 7) + y1) * 32);
            const floatx4* f22 = (const floatx4*)(base + (size_t)((x1 << 7) + y1) * 32);
            float w11 = dxw * dyw;
            float w12 = (1.f - dxw) * dyw;
            float w21 = dxw * (1.f - dyw);
            float w22 = (1.f - dxw) * (1.f - dyw);
            floatx4 a0 = f11[0], a1 = f11[1];
            floatx4 b0v = f12[0], b1v = f12[1];
            floatx4 c0v = f21[0], c1v = f21[1];
            floatx4 d0v = f22[0], d1v = f22[1];
            fe0 += a0 * w11 + b0v * w12 + c0v * w21 + d0v * w22;
            fe1 += a1 * w11 + b1v * w12 + c1v * w21 + d1v * w22;
        }

        // ---- B operand for the K=4 projections: rows 0..3 = (px,py,pz,1) on quad 0
        half8 bp;
        {
            union { half8 v; half2v p2[4]; } u;
            half2v z = {};
            u.p2[0] = (q == 0) ? cvt2(px, py) : z;
            u.p2[1] = (q == 0) ? cvt2(pz, 1.0f) : z;
            u.p2[2] = z; u.p2[3] = z;
            bp = u.v;
        }

        // ---- blk0: hidden layer + 256->32 via MFMA ----
        floatx4 acc0 = b00a, acc1 = b00b;
        #pragma unroll
        for (int cch = 0; cch < 8; cch++) {
            uA ha, hb;
            ha.h[0] = *(const half4v*)(hB0 + cch * 128); ha.h[1] = zh4;
            hb.h[0] = *(const half4v*)(hB1 + cch * 128); hb.h[1] = zh4;
            floatx4 hz = {};
            floatx4 h0 = __builtin_amdgcn_mfma_f32_16x16x32_f16(ha.v, bp, hz, 0, 0, 0);
            floatx4 h1 = __builtin_amdgcn_mfma_f32_16x16x32_f16(hb.v, bp, hz, 0, 0, 0);
            half8 bf = relupack2(h0, h1);
            half8 a0 = *(const half8*)(w0r0 + ((((cch << 2) | q) ^ sw0) << 3));
            half8 a1 = *(const half8*)(w0r1 + ((((cch << 2) | q) ^ sw0) << 3));
            acc0 = __builtin_amdgcn_mfma_f32_16x16x32_f16(a0, bf, acc0, 0, 0, 0);
            acc1 = __builtin_amdgcn_mfma_f32_16x16x32_f16(a1, bf, acc1, 0, 0, 0);
        }

        // ---- st = fold(p)+b0b1 (via MFMA, C=feat) + W1 @ relu(acc) ----
        floatx4 st0 = __builtin_amdgcn_mfma_f32_16x16x32_f16(fA0.v, bp, fe0, 0, 0, 0);
        floatx4 st1 = __builtin_amdgcn_mfma_f32_16x16x32_f16(fA1.v, bp, fe1, 0, 0, 0);
        {
            half8 bf = relupack2(acc0, acc1);
            uA a0, a1;
            a0.h[0] = *(const half4v*)(s_wA + rA + c0);
            a0.h[1] = *(const half4v*)(s_wA + rA + c1);
            a1.h[0] = *(const half4v*)(s_wA + rB + c0);
            a1.h[1] = *(const half4v*)(s_wA + rB + c1);
            st0 = __builtin_amdgcn_mfma_f32_16x16x32_f16(a0.v, bf, st0, 0, 0, 0);
            st1 = __builtin_amdgcn_mfma_f32_16x16x32_f16(a1.v, bf, st1, 0, 0, 0);
        }

        // ---- residual blocks ----
        #pragma unroll
        for (int bk = 0; bk < 4; bk++) {
            const f16* w_a = s_wA + (1 + 2 * bk) * 1024;
            const f16* w_b = s_wA + (2 + 2 * bk) * 1024;
            floatx4 h0 = *(const floatx4*)&s_bb0f[bk * 32 + q * 8];
            floatx4 h1 = *(const floatx4*)&s_bb0f[bk * 32 + q * 8 + 4];
            {
                half8 bf = relupack2(st0, st1);
                uA a0, a1;
                a0.h[0] = *(const half4v*)(w_a + rA + c0);
                a0.h[1] = *(const half4v*)(w_a + rA + c1);
                a1.h[0] = *(const half4v*)(w_a + rB + c0);
                a1.h[1] = *(const half4v*)(w_a + rB + c1);
                h0 = __builtin_amdgcn_mfma_f32_16x16x32_f16(a0.v, bf, h0, 0, 0, 0);
                h1 = __builtin_amdgcn_mfma_f32_16x16x32_f16(a1.v, bf, h1, 0, 0, 0);
            }
            floatx4 d0 = *(const floatx4*)&s_bb1f[bk * 32 + q * 8];
            floatx4 d1 = *(const floatx4*)&s_bb1f[bk * 32 + q * 8 + 4];
            {
                half8 bf = relupack2(h0, h1);
                uA a0, a1;
                a0.h[0] = *(const half4v*)(w_b + rA + c0);
                a0.h[1] = *(const half4v*)(w_b + rA + c1);
                a1.h[0] = *(const half4v*)(w_b + rB + c0);
                a1.h[1] = *(const half4v*)(w_b + rB + c1);
                d0 = __builtin_amdgcn_mfma_f32_16x16x32_f16(a0.v, bf, d0, 0, 0, 0);
                d1 = __builtin_amdgcn_mfma_f32_16x16x32_f16(a1.v, bf, d1, 0, 0, 0);
            }
            st0 += d0 + fe0;
            st1 += d1 + fe1;
        }

        // ---- head ----
        float o = 0.f;
        #pragma unroll
        for (int r = 0; r < 4; r++)
            o += fmaxf(st0[r], 0.f) * fw0[r] + fmaxf(st1[r], 0.f) * fw1[r];
        o += __shfl_xor(o, 16);
        o += __shfl_xor(o, 32);
        if (q == 0 && t < NT) out[(size_t)b * NT + t] = o + s_fob;
    }
}

extern "C" void kernel_launch(void* const* d_in, const int* in_sizes, int n_in,
                              void* d_out, int out_size, void* d_ws, size_t ws_size,
                              hipStream_t stream) {
    const float* p    = (const float*)d_in[0];
    const float* c    = (const float*)d_in[2];
    const float* Cm   = (const float*)d_in[3];
    const float* fpw  = (const float*)d_in[4];
    const float* fpb  = (const float*)d_in[5];
    const float* b0w0 = (const float*)d_in[6];
    const float* b0b0 = (const float*)d_in[7];
    const float* b0w1 = (const float*)d_in[8];
    const float* b0b1 = (const float*)d_in[9];
    const float* b0ws = (const float*)d_in[10];
    const float* bw0  = (const float*)d_in[11];
    const float* bb0  = (const float*)d_in[12];
    const float* bw1  = (const float*)d_in[13];
    const float* bb1  = (const float*)d_in[14];
    const float* fow  = (const float*)d_in[15];
    const float* fob  = (const float*)d_in[16];
    floatx4* fold = (floatx4*)d_ws;

    fold_kernel<<<1, 256, 0, stream>>>(b0ws, fpw, fpb, fold);

    dim3 grid((NT + 127) / 128, NB);
    decoder_kernel<<<grid, 256, 0, stream>>>(p, c, Cm, fpw, fpb,
                                             b0w0, b0b0, b0w1, b0b1,
                                             bw0, bb0, bw1, bb1,
                                             fow, fob, fold, (float*)d_out);
}

// Round 5
// 391.912 us; speedup vs baseline: 1.1938x; 1.0242x over previous
//
#include <hip/hip_runtime.h>

#define NB 8
#define NT 30000
#define NL 6
#define NC 32
#define NHID 256

typedef _Float16 f16;
typedef f16 half8 __attribute__((ext_vector_type(8)));
typedef f16 half4v __attribute__((ext_vector_type(4)));
typedef f16 half2v __attribute__((ext_vector_type(2)));
typedef float floatx4 __attribute__((ext_vector_type(4)));

// Row permutation so MFMA D-layout lands in "lane(q) owns channels 8q..8q+7" order.
__device__ __forceinline__ int permrow(int m) {
    return 8 * ((m & 15) >> 2) + 4 * (m >> 4) + (m & 3);
}

__device__ __forceinline__ half2v cvt2(float a, float b) {
    return __builtin_bit_cast(half2v, __builtin_amdgcn_cvt_pkrtz(a, b));
}

// relu + pack two floatx4 -> half8, register-only (shufflevector, no unions/arrays)
__device__ __forceinline__ half8 relupack2(floatx4 a, floatx4 b) {
    half2v p0 = cvt2(fmaxf(a[0], 0.f), fmaxf(a[1], 0.f));
    half2v p1 = cvt2(fmaxf(a[2], 0.f), fmaxf(a[3], 0.f));
    half2v p2 = cvt2(fmaxf(b[0], 0.f), fmaxf(b[1], 0.f));
    half2v p3 = cvt2(fmaxf(b[2], 0.f), fmaxf(b[3], 0.f));
    half4v q0 = __builtin_shufflevector(p0, p1, 0, 1, 2, 3);
    half4v q1 = __builtin_shufflevector(p2, p3, 0, 1, 2, 3);
    return __builtin_shufflevector(q0, q1, 0, 1, 2, 3, 4, 5, 6, 7);
}

// zero-extend half4v -> half8 (hi half zero), register-only
__device__ __forceinline__ half8 zext4(half4v lo) {
    const half4v zh = {};
    return __builtin_shufflevector(lo, zh, 0, 1, 2, 3, 4, 5, 6, 7);
}

// Parallel fold: M = blk0_ws @ fc_p_w (32x3), v = blk0_ws @ fc_p_b. 256 threads.
__global__ void fold_kernel(const float* __restrict__ ws, const float* __restrict__ fpw,
                            const float* __restrict__ fpb, floatx4* __restrict__ out) {
    __shared__ floatx4 s_part[8][32];
    int tid = threadIdx.x;
    int i = tid & 31, kc = tid >> 5;
    const float* wrow = ws + i * 256 + kc * 32;
    const float* pw = fpw + kc * 96;
    const float* pb = fpb + kc * 32;
    floatx4 acc = {};
    #pragma unroll 8
    for (int k = 0; k < 32; k++) {
        float w = wrow[k];
        acc[0] = fmaf(w, pw[k * 3 + 0], acc[0]);
        acc[1] = fmaf(w, pw[k * 3 + 1], acc[1]);
        acc[2] = fmaf(w, pw[k * 3 + 2], acc[2]);
        acc[3] = fmaf(w, pb[k], acc[3]);
    }
    s_part[kc][i] = acc;
    __syncthreads();
    if (kc == 0) {
        floatx4 s = s_part[0][i];
        #pragma unroll
        for (int j = 1; j < 8; j++) s += s_part[j][i];
        out[i] = s;
    }
}

__launch_bounds__(256, 3)
__global__ void decoder_kernel(
    const float* __restrict__ p, const float* __restrict__ c, const float* __restrict__ Cm,
    const float* __restrict__ fpw, const float* __restrict__ fpb,
    const float* __restrict__ b0w0, const float* __restrict__ b0b0,
    const float* __restrict__ b0w1, const float* __restrict__ b0b1,
    const float* __restrict__ bw0, const float* __restrict__ bb0,
    const float* __restrict__ bw1, const float* __restrict__ bb1,
    const float* __restrict__ fow, const float* __restrict__ fob,
    const floatx4* __restrict__ fold, float* __restrict__ out)
{
    __shared__ __align__(16) f16 s_w0A[32 * 256];   // 16 KB; b128 chunk c -> c ^ (m&7)
    __shared__ __align__(16) f16 s_wA[9 * 32 * 32]; // 18 KB; b128 chunk c -> c ^ ((m>>1)&3)
    __shared__ __align__(16) f16 s_hB[256 * 4];     // 2 KB; hidden {w0,w1,w2,b} rows
    __shared__ __align__(16) f16 s_foldA[32 * 4];   // 256 B; {M0,M1,M2,v+b0b1}
    __shared__ __align__(16) float s_b0b0[32], s_fow[32];
    __shared__ __align__(16) float s_bb0f[128], s_bb1f[128];
    __shared__ float s_cam[NL][8];
    __shared__ float s_fob;

    const int tid = threadIdx.x;
    const int b = blockIdx.y;

    // ---- staging ----
    {   // s_w0A: row m = tid>>3, seg = tid&7 -> 4 b128 chunks, slot = chunk ^ (m&7)
        int m = tid >> 3, seg = tid & 7;
        const float* src = b0w0 + permrow(m) * 256 + seg * 32;
        f16* dst = s_w0A + m * 256;
        int sw = m & 7;
        #pragma unroll
        for (int ci = 0; ci < 4; ci++) {
            int cidx = seg * 4 + ci;
            floatx4 f0 = *(const floatx4*)(src + ci * 8);
            floatx4 f1 = *(const floatx4*)(src + ci * 8 + 4);
            half2v h0 = cvt2(f0[0], f0[1]), h1 = cvt2(f0[2], f0[3]);
            half2v h2 = cvt2(f1[0], f1[1]), h3 = cvt2(f1[2], f1[3]);
            half4v q0 = __builtin_shufflevector(h0, h1, 0, 1, 2, 3);
            half4v q1 = __builtin_shufflevector(h2, h3, 0, 1, 2, 3);
            half8 h = __builtin_shufflevector(q0, q1, 0, 1, 2, 3, 4, 5, 6, 7);
            *(half8*)(dst + ((cidx ^ sw) << 3)) = h;
        }
    }
    // s_wA: 9 mats x 32 rows; 4 b128 chunks per row at slot c ^ ((m>>1)&3)
    for (int r = tid; r < 288; r += 256) {
        int mi = r >> 5, m = r & 31;
        int pm = permrow(m);
        const float* src;
        if (mi == 0) src = b0w1 + pm * 32;
        else {
            int mat = mi - 1, bi = mat >> 1;
            src = ((mat & 1) ? bw1 : bw0) + (bi * 32 + pm) * 32;
        }
        f16* dst = s_wA + mi * 1024 + m * 32;
        int sw = (m >> 1) & 3;
        #pragma unroll
        for (int ci = 0; ci < 4; ci++) {
            floatx4 f0 = *(const floatx4*)(src + ci * 8);
            floatx4 f1 = *(const floatx4*)(src + ci * 8 + 4);
            half2v h0 = cvt2(f0[0], f0[1]), h1 = cvt2(f0[2], f0[3]);
            half2v h2 = cvt2(f1[0], f1[1]), h3 = cvt2(f1[2], f1[3]);
            half4v q0 = __builtin_shufflevector(h0, h1, 0, 1, 2, 3);
            half4v q1 = __builtin_shufflevector(h2, h3, 0, 1, 2, 3);
            half8 h = __builtin_shufflevector(q0, q1, 0, 1, 2, 3, 4, 5, 6, 7);
            *(half8*)(dst + ((ci ^ sw) << 3)) = h;
        }
    }
    {   // s_hB: row tid = (cch,m) holds hidden h = cch*32 + permrow(m)
        int cch = tid >> 5, m = tid & 31;
        int h = cch * 32 + permrow(m);
        half2v a = cvt2(fpw[h * 3 + 0], fpw[h * 3 + 1]);
        half2v bq = cvt2(fpw[h * 3 + 2], fpb[h]);
        *(half4v*)(s_hB + tid * 4) = __builtin_shufflevector(a, bq, 0, 1, 2, 3);
    }
    if (tid < 32) {
        int pm = permrow(tid);
        floatx4 f = fold[pm];
        half2v a = cvt2(f[0], f[1]);
        half2v bq = cvt2(f[2], f[3] + b0b1[pm]);
        *(half4v*)(s_foldA + tid * 4) = __builtin_shufflevector(a, bq, 0, 1, 2, 3);
        s_b0b0[tid] = b0b0[tid];
        s_fow[tid]  = fow[tid];
    }
    if (tid >= 64 && tid < 192) {
        int j = tid - 64;
        s_bb0f[j] = bb0[j];
        s_bb1f[j] = bb1[j];
    }
    if (tid == 0) s_fob = fob[0];
    if (tid >= 192 && tid < 192 + NL) {
        int l = tid - 192;
        const float* cm = Cm + ((size_t)b * NL + l) * 12;
        float denom = cm[9] + 0.05f;
        float s = 63.5f / (0.55f * denom);
        s_cam[l][0] = cm[0] * s; s_cam[l][1] = cm[1] * s; s_cam[l][2] = cm[2] * s;
        s_cam[l][3] = cm[3] * s; s_cam[l][4] = cm[4] * s; s_cam[l][5] = cm[5] * s;
    }
    __syncthreads();

    const int lane = tid & 63;
    const int wv = tid >> 6;
    const int q = lane >> 4;
    const int i16 = lane & 15;
    const int sw0 = i16 & 7;

    // group-invariant LDS bases/offsets (single-b128 A-frag reads everywhere)
    const f16* w0r0 = s_w0A + i16 * 256;
    const f16* w0r1 = s_w0A + (16 + i16) * 256;
    const int qsw = (q ^ ((i16 >> 1) & 3)) << 3;
    const int soff0 = i16 * 32 + qsw;
    const int soff1 = (16 + i16) * 32 + qsw;
    const f16* hB0 = s_hB + i16 * 4;
    const f16* hB1 = s_hB + (16 + i16) * 4;
    const float* cq = c + (((size_t)b * NL) << 19) + q * 8;

    // fold A-frags (g-invariant), hi halves zero (B rows 4..31 are exactly 0)
    const half8 fA0 = zext4(*(const half4v*)(s_foldA + i16 * 4));
    const half8 fA1 = zext4(*(const half4v*)(s_foldA + (16 + i16) * 4));
    const floatx4 fw0 = *(const floatx4*)&s_fow[q * 8];
    const floatx4 fw1 = *(const floatx4*)&s_fow[q * 8 + 4];
    const floatx4 b00a = *(const floatx4*)&s_b0b0[q * 8];
    const floatx4 b00b = *(const floatx4*)&s_b0b0[q * 8 + 4];

    #pragma unroll 1
    for (int g = 0; g < 2; g++) {
        const int t = blockIdx.x * 128 + (g * 4 + wv) * 16 + i16;
        const int tc = min(t, NT - 1);
        const float* pp = p + ((size_t)b * NT + tc) * 3;
        float px = pp[0], py = pp[1], pz = pp[2];

        // ---- bilinear multi-view gather (lane: its 8 channels) ----
        floatx4 fe0 = {}, fe1 = {};
        #pragma unroll 1
        for (int l = 0; l < NL; l++) {
            float x = s_cam[l][0] * px + s_cam[l][1] * py + s_cam[l][2] * pz + 63.5f;
            float y = s_cam[l][3] * px + s_cam[l][4] * py + s_cam[l][5] * pz + 63.5f;
            float x0f = floorf(x), x1f = ceilf(x);
            float y0f = floorf(y), y1f = ceilf(y);
            float dxw = x1f - x, dyw = y1f - y;
            int x0 = min(max((int)x0f, 0), 127);
            int x1 = min(max((int)x1f, 0), 127);
            int y0 = min(max((int)y0f, 0), 127);
            int y1 = min(max((int)y1f, 0), 127);
            const float* base = cq + ((size_t)l << 19);
            const floatx4* f11 = (const floatx4*)(base + (size_t)((x0 << 7) + y0) * 32);
            const floatx4* f12 = (const floatx4*)(base + (size_t)((x1 << 7) + y0) * 32);
            const floatx4* f21 = (const floatx4*)(base + (size_t)((x0 << 7) + y1) * 32);
            const floatx4* f22 = (const floatx4*)(base + (size_t)((x1 << 7) + y1) * 32);
            float w11 = dxw * dyw;
            float w12 = (1.f - dxw) * dyw;
            float w21 = dxw * (1.f - dyw);
            float w22 = (1.f - dxw) * (1.f - dyw);
            floatx4 a0 = f11[0], a1 = f11[1];
            floatx4 b0v = f12[0], b1v = f12[1];
            floatx4 c0v = f21[0], c1v = f21[1];
            floatx4 d0v = f22[0], d1v = f22[1];
            fe0 += a0 * w11 + b0v * w12 + c0v * w21 + d0v * w22;
            fe1 += a1 * w11 + b1v * w12 + c1v * w21 + d1v * w22;
        }

        // ---- B operand for K=4 projections: rows 0..3 = (px,py,pz,1) on quad 0 ----
        half8 bp;
        {
            half2v xy = cvt2(px, py), z1 = cvt2(pz, 1.0f);
            half4v lo = __builtin_shufflevector(xy, z1, 0, 1, 2, 3);
            half8 full = zext4(lo);
            const half8 zh8 = {};
            bp = (q == 0) ? full : zh8;
        }

        // ---- blk0: hidden layer (via MFMA) + 256->32 ----
        floatx4 acc0 = b00a, acc1 = b00b;
        #pragma unroll
        for (int cch = 0; cch < 8; cch++) {
            half8 ha = zext4(*(const half4v*)(hB0 + cch * 128));
            half8 hb = zext4(*(const half4v*)(hB1 + cch * 128));
            floatx4 hz = {};
            floatx4 h0 = __builtin_amdgcn_mfma_f32_16x16x32_f16(ha, bp, hz, 0, 0, 0);
            floatx4 h1 = __builtin_amdgcn_mfma_f32_16x16x32_f16(hb, bp, hz, 0, 0, 0);
            half8 bf = relupack2(h0, h1);
            half8 a0 = *(const half8*)(w0r0 + ((((cch << 2) | q) ^ sw0) << 3));
            half8 a1 = *(const half8*)(w0r1 + ((((cch << 2) | q) ^ sw0) << 3));
            acc0 = __builtin_amdgcn_mfma_f32_16x16x32_f16(a0, bf, acc0, 0, 0, 0);
            acc1 = __builtin_amdgcn_mfma_f32_16x16x32_f16(a1, bf, acc1, 0, 0, 0);
        }

        // ---- st = fold(p)+b0b1 (MFMA, C=feat) + W1 @ relu(acc) ----
        floatx4 st0 = __builtin_amdgcn_mfma_f32_16x16x32_f16(fA0, bp, fe0, 0, 0, 0);
        floatx4 st1 = __builtin_amdgcn_mfma_f32_16x16x32_f16(fA1, bp, fe1, 0, 0, 0);
        {
            half8 bf = relupack2(acc0, acc1);
            half8 a0 = *(const half8*)(s_wA + soff0);
            half8 a1 = *(const half8*)(s_wA + soff1);
            st0 = __builtin_amdgcn_mfma_f32_16x16x32_f16(a0, bf, st0, 0, 0, 0);
            st1 = __builtin_amdgcn_mfma_f32_16x16x32_f16(a1, bf, st1, 0, 0, 0);
        }

        // ---- residual blocks ----
        #pragma unroll
        for (int bk = 0; bk < 4; bk++) {
            const f16* w_a = s_wA + (1 + 2 * bk) * 1024;
            const f16* w_b = s_wA + (2 + 2 * bk) * 1024;
            floatx4 h0 = *(const floatx4*)&s_bb0f[bk * 32 + q * 8];
            floatx4 h1 = *(const floatx4*)&s_bb0f[bk * 32 + q * 8 + 4];
            {
                half8 bf = relupack2(st0, st1);
                half8 a0 = *(const half8*)(w_a + soff0);
                half8 a1 = *(const half8*)(w_a + soff1);
                h0 = __builtin_amdgcn_mfma_f32_16x16x32_f16(a0, bf, h0, 0, 0, 0);
                h1 = __builtin_amdgcn_mfma_f32_16x16x32_f16(a1, bf, h1, 0, 0, 0);
            }
            floatx4 d0 = *(const floatx4*)&s_bb1f[bk * 32 + q * 8];
            floatx4 d1 = *(const floatx4*)&s_bb1f[bk * 32 + q * 8 + 4];
            {
                half8 bf = relupack2(h0, h1);
                half8 a0 = *(const half8*)(w_b + soff0);
                half8 a1 = *(const half8*)(w_b + soff1);
                d0 = __builtin_amdgcn_mfma_f32_16x16x32_f16(a0, bf, d0, 0, 0, 0);
                d1 = __builtin_amdgcn_mfma_f32_16x16x32_f16(a1, bf, d1, 0, 0, 0);
            }
            st0 += d0 + fe0;
            st1 += d1 + fe1;
        }

        // ---- head ----
        float o = 0.f;
        #pragma unroll
        for (int r = 0; r < 4; r++)
            o += fmaxf(st0[r], 0.f) * fw0[r] + fmaxf(st1[r], 0.f) * fw1[r];
        o += __shfl_xor(o, 16);
        o += __shfl_xor(o, 32);
        if (q == 0 && t < NT) out[(size_t)b * NT + t] = o + s_fob;
    }
}

extern "C" void kernel_launch(void* const* d_in, const int* in_sizes, int n_in,
                              void* d_out, int out_size, void* d_ws, size_t ws_size,
                              hipStream_t stream) {
    const float* p    = (const float*)d_in[0];
    const float* c    = (const float*)d_in[2];
    const float* Cm   = (const float*)d_in[3];
    const float* fpw  = (const float*)d_in[4];
    const float* fpb  = (const float*)d_in[5];
    const float* b0w0 = (const float*)d_in[6];
    const float* b0b0 = (const float*)d_in[7];
    const float* b0w1 = (const float*)d_in[8];
    const float* b0b1 = (const float*)d_in[9];
    const float* b0ws = (const float*)d_in[10];
    const float* bw0  = (const float*)d_in[11];
    const float* bb0  = (const float*)d_in[12];
    const float* bw1  = (const float*)d_in[13];
    const float* bb1  = (const float*)d_in[14];
    const float* fow  = (const float*)d_in[15];
    const float* fob  = (const float*)d_in[16];
    floatx4* fold = (floatx4*)d_ws;

    fold_kernel<<<1, 256, 0, stream>>>(b0ws, fpw, fpb, fold);

    dim3 grid((NT + 127) / 128, NB);
    decoder_kernel<<<grid, 256, 0, stream>>>(p, c, Cm, fpw, fpb,
                                             b0w0, b0b0, b0w1, b0b1,
                                             bw0, bb0, bw1, bb1,
                                             fow, fob, fold, (float*)d_out);
}

// Round 6
// 267.379 us; speedup vs baseline: 1.7498x; 1.4658x over previous
//
#include <hip/hip_runtime.h>

#define NB 8
#define NT 30000
#define NL 6
#define NC 32
#define NHID 256

typedef _Float16 f16;
typedef f16 half8 __attribute__((ext_vector_type(8)));
typedef f16 half4v __attribute__((ext_vector_type(4)));
typedef f16 half2v __attribute__((ext_vector_type(2)));
typedef float floatx4 __attribute__((ext_vector_type(4)));

// Row permutation so MFMA D-layout lands in "lane(q) owns channels 8q..8q+7" order.
__device__ __forceinline__ int permrow(int m) {
    return 8 * ((m & 15) >> 2) + 4 * (m >> 4) + (m & 3);
}

__device__ __forceinline__ half2v cvt2(float a, float b) {
    return __builtin_bit_cast(half2v, __builtin_amdgcn_cvt_pkrtz(a, b));
}

// relu + pack two floatx4 -> half8, register-only (shufflevector, no unions/arrays)
__device__ __forceinline__ half8 relupack2(floatx4 a, floatx4 b) {
    half2v p0 = cvt2(fmaxf(a[0], 0.f), fmaxf(a[1], 0.f));
    half2v p1 = cvt2(fmaxf(a[2], 0.f), fmaxf(a[3], 0.f));
    half2v p2 = cvt2(fmaxf(b[0], 0.f), fmaxf(b[1], 0.f));
    half2v p3 = cvt2(fmaxf(b[2], 0.f), fmaxf(b[3], 0.f));
    half4v q0 = __builtin_shufflevector(p0, p1, 0, 1, 2, 3);
    half4v q1 = __builtin_shufflevector(p2, p3, 0, 1, 2, 3);
    return __builtin_shufflevector(q0, q1, 0, 1, 2, 3, 4, 5, 6, 7);
}

// zero-extend half4v -> half8 (hi half zero), register-only
__device__ __forceinline__ half8 zext4(half4v lo) {
    const half4v zh = {};
    return __builtin_shufflevector(lo, zh, 0, 1, 2, 3, 4, 5, 6, 7);
}

// Parallel fold: M = blk0_ws @ fc_p_w (32x3), v = blk0_ws @ fc_p_b. 256 threads.
__global__ void fold_kernel(const float* __restrict__ ws, const float* __restrict__ fpw,
                            const float* __restrict__ fpb, floatx4* __restrict__ out) {
    __shared__ floatx4 s_part[8][32];
    int tid = threadIdx.x;
    int i = tid & 31, kc = tid >> 5;
    const float* wrow = ws + i * 256 + kc * 32;
    const float* pw = fpw + kc * 96;
    const float* pb = fpb + kc * 32;
    floatx4 acc = {};
    #pragma unroll 8
    for (int k = 0; k < 32; k++) {
        float w = wrow[k];
        acc[0] = fmaf(w, pw[k * 3 + 0], acc[0]);
        acc[1] = fmaf(w, pw[k * 3 + 1], acc[1]);
        acc[2] = fmaf(w, pw[k * 3 + 2], acc[2]);
        acc[3] = fmaf(w, pb[k], acc[3]);
    }
    s_part[kc][i] = acc;
    __syncthreads();
    if (kc == 0) {
        floatx4 s = s_part[0][i];
        #pragma unroll
        for (int j = 1; j < 8; j++) s += s_part[j][i];
        out[i] = s;
    }
}

// (256, 2): register cap 256 for the UNIFIED arch-VGPR + AGPR budget.
// (256, 3) capped at 168 and the MFMA accumulators pushed total past the cap
// -> 341 MB of scratch spill traffic per dispatch (rounds 3-5).
__launch_bounds__(256, 2)
__global__ void decoder_kernel(
    const float* __restrict__ p, const float* __restrict__ c, const float* __restrict__ Cm,
    const float* __restrict__ fpw, const float* __restrict__ fpb,
    const float* __restrict__ b0w0, const float* __restrict__ b0b0,
    const float* __restrict__ b0w1, const float* __restrict__ b0b1,
    const float* __restrict__ bw0, const float* __restrict__ bb0,
    const float* __restrict__ bw1, const float* __restrict__ bb1,
    const float* __restrict__ fow, const float* __restrict__ fob,
    const floatx4* __restrict__ fold, float* __restrict__ out)
{
    __shared__ __align__(16) f16 s_w0A[32 * 256];   // 16 KB; b128 chunk c -> c ^ (m&7)
    __shared__ __align__(16) f16 s_wA[9 * 32 * 32]; // 18 KB; b128 chunk c -> c ^ ((m>>1)&3)
    __shared__ __align__(16) f16 s_hB[256 * 4];     // 2 KB; hidden {w0,w1,w2,b} rows
    __shared__ __align__(16) f16 s_foldA[32 * 4];   // 256 B; {M0,M1,M2,v+b0b1}
    __shared__ __align__(16) float s_b0b0[32], s_fow[32];
    __shared__ __align__(16) float s_bb0f[128], s_bb1f[128];
    __shared__ float s_cam[NL][8];
    __shared__ float s_fob;

    const int tid = threadIdx.x;
    const int b = blockIdx.y;

    // ---- staging ----
    {   // s_w0A: row m = tid>>3, seg = tid&7 -> 4 b128 chunks, slot = chunk ^ (m&7)
        int m = tid >> 3, seg = tid & 7;
        const float* src = b0w0 + permrow(m) * 256 + seg * 32;
        f16* dst = s_w0A + m * 256;
        int sw = m & 7;
        #pragma unroll
        for (int ci = 0; ci < 4; ci++) {
            int cidx = seg * 4 + ci;
            floatx4 f0 = *(const floatx4*)(src + ci * 8);
            floatx4 f1 = *(const floatx4*)(src + ci * 8 + 4);
            half2v h0 = cvt2(f0[0], f0[1]), h1 = cvt2(f0[2], f0[3]);
            half2v h2 = cvt2(f1[0], f1[1]), h3 = cvt2(f1[2], f1[3]);
            half4v q0 = __builtin_shufflevector(h0, h1, 0, 1, 2, 3);
            half4v q1 = __builtin_shufflevector(h2, h3, 0, 1, 2, 3);
            half8 h = __builtin_shufflevector(q0, q1, 0, 1, 2, 3, 4, 5, 6, 7);
            *(half8*)(dst + ((cidx ^ sw) << 3)) = h;
        }
    }
    // s_wA: 9 mats x 32 rows; 4 b128 chunks per row at slot c ^ ((m>>1)&3)
    for (int r = tid; r < 288; r += 256) {
        int mi = r >> 5, m = r & 31;
        int pm = permrow(m);
        const float* src;
        if (mi == 0) src = b0w1 + pm * 32;
        else {
            int mat = mi - 1, bi = mat >> 1;
            src = ((mat & 1) ? bw1 : bw0) + (bi * 32 + pm) * 32;
        }
        f16* dst = s_wA + mi * 1024 + m * 32;
        int sw = (m >> 1) & 3;
        #pragma unroll
        for (int ci = 0; ci < 4; ci++) {
            floatx4 f0 = *(const floatx4*)(src + ci * 8);
            floatx4 f1 = *(const floatx4*)(src + ci * 8 + 4);
            half2v h0 = cvt2(f0[0], f0[1]), h1 = cvt2(f0[2], f0[3]);
            half2v h2 = cvt2(f1[0], f1[1]), h3 = cvt2(f1[2], f1[3]);
            half4v q0 = __builtin_shufflevector(h0, h1, 0, 1, 2, 3);
            half4v q1 = __builtin_shufflevector(h2, h3, 0, 1, 2, 3);
            half8 h = __builtin_shufflevector(q0, q1, 0, 1, 2, 3, 4, 5, 6, 7);
            *(half8*)(dst + ((ci ^ sw) << 3)) = h;
        }
    }
    {   // s_hB: row tid = (cch,m) holds hidden h = cch*32 + permrow(m)
        int cch = tid >> 5, m = tid & 31;
        int h = cch * 32 + permrow(m);
        half2v a = cvt2(fpw[h * 3 + 0], fpw[h * 3 + 1]);
        half2v bq = cvt2(fpw[h * 3 + 2], fpb[h]);
        *(half4v*)(s_hB + tid * 4) = __builtin_shufflevector(a, bq, 0, 1, 2, 3);
    }
    if (tid < 32) {
        int pm = permrow(tid);
        floatx4 f = fold[pm];
        half2v a = cvt2(f[0], f[1]);
        half2v bq = cvt2(f[2], f[3] + b0b1[pm]);
        *(half4v*)(s_foldA + tid * 4) = __builtin_shufflevector(a, bq, 0, 1, 2, 3);
        s_b0b0[tid] = b0b0[tid];
        s_fow[tid]  = fow[tid];
    }
    if (tid >= 64 && tid < 192) {
        int j = tid - 64;
        s_bb0f[j] = bb0[j];
        s_bb1f[j] = bb1[j];
    }
    if (tid == 0) s_fob = fob[0];
    if (tid >= 192 && tid < 192 + NL) {
        int l = tid - 192;
        const float* cm = Cm + ((size_t)b * NL + l) * 12;
        float denom = cm[9] + 0.05f;
        float s = 63.5f / (0.55f * denom);
        s_cam[l][0] = cm[0] * s; s_cam[l][1] = cm[1] * s; s_cam[l][2] = cm[2] * s;
        s_cam[l][3] = cm[3] * s; s_cam[l][4] = cm[4] * s; s_cam[l][5] = cm[5] * s;
    }
    __syncthreads();

    const int lane = tid & 63;
    const int wv = tid >> 6;
    const int q = lane >> 4;
    const int i16 = lane & 15;
    const int sw0 = i16 & 7;

    // group-invariant LDS bases/offsets (single-b128 A-frag reads everywhere)
    const f16* w0r0 = s_w0A + i16 * 256;
    const f16* w0r1 = s_w0A + (16 + i16) * 256;
    const int qsw = (q ^ ((i16 >> 1) & 3)) << 3;
    const int soff0 = i16 * 32 + qsw;
    const int soff1 = (16 + i16) * 32 + qsw;
    const f16* hB0 = s_hB + i16 * 4;
    const f16* hB1 = s_hB + (16 + i16) * 4;
    const float* cq = c + (((size_t)b * NL) << 19) + q * 8;

    // fold A-frags (g-invariant), hi halves zero (B rows 4..31 are exactly 0)
    const half8 fA0 = zext4(*(const half4v*)(s_foldA + i16 * 4));
    const half8 fA1 = zext4(*(const half4v*)(s_foldA + (16 + i16) * 4));
    const floatx4 fw0 = *(const floatx4*)&s_fow[q * 8];
    const floatx4 fw1 = *(const floatx4*)&s_fow[q * 8 + 4];
    const floatx4 b00a = *(const floatx4*)&s_b0b0[q * 8];
    const floatx4 b00b = *(const floatx4*)&s_b0b0[q * 8 + 4];

    #pragma unroll 1
    for (int g = 0; g < 2; g++) {
        const int t = blockIdx.x * 128 + (g * 4 + wv) * 16 + i16;
        const int tc = min(t, NT - 1);
        const float* pp = p + ((size_t)b * NT + tc) * 3;
        float px = pp[0], py = pp[1], pz = pp[2];

        // ---- bilinear multi-view gather (lane: its 8 channels) ----
        floatx4 fe0 = {}, fe1 = {};
        #pragma unroll 1
        for (int l = 0; l < NL; l++) {
            float x = s_cam[l][0] * px + s_cam[l][1] * py + s_cam[l][2] * pz + 63.5f;
            float y = s_cam[l][3] * px + s_cam[l][4] * py + s_cam[l][5] * pz + 63.5f;
            float x0f = floorf(x), x1f = ceilf(x);
            float y0f = floorf(y), y1f = ceilf(y);
            float dxw = x1f - x, dyw = y1f - y;
            int x0 = min(max((int)x0f, 0), 127);
            int x1 = min(max((int)x1f, 0), 127);
            int y0 = min(max((int)y0f, 0), 127);
            int y1 = min(max((int)y1f, 0), 127);
            const float* base = cq + ((size_t)l << 19);
            const floatx4* f11 = (const floatx4*)(base + (size_t)((x0 << 7) + y0) * 32);
            const floatx4* f12 = (const floatx4*)(base + (size_t)((x1 << 7) + y0) * 32);
            const floatx4* f21 = (const floatx4*)(base + (size_t)((x0 << 7) + y1) * 32);
            const floatx4* f22 = (const floatx4*)(base + (size_t)((x1 << 7) + y1) * 32);
            float w11 = dxw * dyw;
            float w12 = (1.f - dxw) * dyw;
            float w21 = dxw * (1.f - dyw);
            float w22 = (1.f - dxw) * (1.f - dyw);
            floatx4 a0 = f11[0], a1 = f11[1];
            floatx4 b0v = f12[0], b1v = f12[1];
            floatx4 c0v = f21[0], c1v = f21[1];
            floatx4 d0v = f22[0], d1v = f22[1];
            fe0 += a0 * w11 + b0v * w12 + c0v * w21 + d0v * w22;
            fe1 += a1 * w11 + b1v * w12 + c1v * w21 + d1v * w22;
        }

        // ---- B operand for K=4 projections: rows 0..3 = (px,py,pz,1) on quad 0 ----
        half8 bp;
        {
            half2v xy = cvt2(px, py), z1 = cvt2(pz, 1.0f);
            half4v lo = __builtin_shufflevector(xy, z1, 0, 1, 2, 3);
            half8 full = zext4(lo);
            const half8 zh8 = {};
            bp = (q == 0) ? full : zh8;
        }

        // ---- blk0: hidden layer (via MFMA) + 256->32 ----
        floatx4 acc0 = b00a, acc1 = b00b;
        #pragma unroll 2
        for (int cch = 0; cch < 8; cch++) {
            half8 ha = zext4(*(const half4v*)(hB0 + cch * 128));
            half8 hb = zext4(*(const half4v*)(hB1 + cch * 128));
            floatx4 hz = {};
            floatx4 h0 = __builtin_amdgcn_mfma_f32_16x16x32_f16(ha, bp, hz, 0, 0, 0);
            floatx4 h1 = __builtin_amdgcn_mfma_f32_16x16x32_f16(hb, bp, hz, 0, 0, 0);
            half8 bf = relupack2(h0, h1);
            half8 a0 = *(const half8*)(w0r0 + ((((cch << 2) | q) ^ sw0) << 3));
            half8 a1 = *(const half8*)(w0r1 + ((((cch << 2) | q) ^ sw0) << 3));
            acc0 = __builtin_amdgcn_mfma_f32_16x16x32_f16(a0, bf, acc0, 0, 0, 0);
            acc1 = __builtin_amdgcn_mfma_f32_16x16x32_f16(a1, bf, acc1, 0, 0, 0);
        }

        // ---- st = fold(p)+b0b1 (MFMA, C=feat) + W1 @ relu(acc) ----
        floatx4 st0 = __builtin_amdgcn_mfma_f32_16x16x32_f16(fA0, bp, fe0, 0, 0, 0);
        floatx4 st1 = __builtin_amdgcn_mfma_f32_16x16x32_f16(fA1, bp, fe1, 0, 0, 0);
        {
            half8 bf = relupack2(acc0, acc1);
            half8 a0 = *(const half8*)(s_wA + soff0);
            half8 a1 = *(const half8*)(s_wA + soff1);
            st0 = __builtin_amdgcn_mfma_f32_16x16x32_f16(a0, bf, st0, 0, 0, 0);
            st1 = __builtin_amdgcn_mfma_f32_16x16x32_f16(a1, bf, st1, 0, 0, 0);
        }

        // ---- residual blocks ----
        #pragma unroll
        for (int bk = 0; bk < 4; bk++) {
            const f16* w_a = s_wA + (1 + 2 * bk) * 1024;
            const f16* w_b = s_wA + (2 + 2 * bk) * 1024;
            floatx4 h0 = *(const floatx4*)&s_bb0f[bk * 32 + q * 8];
            floatx4 h1 = *(const floatx4*)&s_bb0f[bk * 32 + q * 8 + 4];
            {
                half8 bf = relupack2(st0, st1);
                half8 a0 = *(const half8*)(w_a + soff0);
                half8 a1 = *(const half8*)(w_a + soff1);
                h0 = __builtin_amdgcn_mfma_f32_16x16x32_f16(a0, bf, h0, 0, 0, 0);
                h1 = __builtin_amdgcn_mfma_f32_16x16x32_f16(a1, bf, h1, 0, 0, 0);
            }
            floatx4 d0 = *(const floatx4*)&s_bb1f[bk * 32 + q * 8];
            floatx4 d1 = *(const floatx4*)&s_bb1f[bk * 32 + q * 8 + 4];
            {
                half8 bf = relupack2(h0, h1);
                half8 a0 = *(const half8*)(w_b + soff0);
                half8 a1 = *(const half8*)(w_b + soff1);
                d0 = __builtin_amdgcn_mfma_f32_16x16x32_f16(a0, bf, d0, 0, 0, 0);
                d1 = __builtin_amdgcn_mfma_f32_16x16x32_f16(a1, bf, d1, 0, 0, 0);
            }
            st0 += d0 + fe0;
            st1 += d1 + fe1;
        }

        // ---- head ----
        float o = 0.f;
        #pragma unroll
        for (int r = 0; r < 4; r++)
            o += fmaxf(st0[r], 0.f) * fw0[r] + fmaxf(st1[r], 0.f) * fw1[r];
        o += __shfl_xor(o, 16);
        o += __shfl_xor(o, 32);
        if (q == 0 && t < NT) out[(size_t)b * NT + t] = o + s_fob;
    }
}

extern "C" void kernel_launch(void* const* d_in, const int* in_sizes, int n_in,
                              void* d_out, int out_size, void* d_ws, size_t ws_size,
                              hipStream_t stream) {
    const float* p    = (const float*)d_in[0];
    const float* c    = (const float*)d_in[2];
    const float* Cm   = (const float*)d_in[3];
    const float* fpw  = (const float*)d_in[4];
    const float* fpb  = (const float*)d_in[5];
    const float* b0w0 = (const float*)d_in[6];
    const float* b0b0 = (const float*)d_in[7];
    const float* b0w1 = (const float*)d_in[8];
    const float* b0b1 = (const float*)d_in[9];
    const float* b0ws = (const float*)d_in[10];
    const float* bw0  = (const float*)d_in[11];
    const float* bb0  = (const float*)d_in[12];
    const float* bw1  = (const float*)d_in[13];
    const float* bb1  = (const float*)d_in[14];
    const float* fow  = (const float*)d_in[15];
    const float* fob  = (const float*)d_in[16];
    floatx4* fold = (floatx4*)d_ws;

    fold_kernel<<<1, 256, 0, stream>>>(b0ws, fpw, fpb, fold);

    dim3 grid((NT + 127) / 128, NB);
    decoder_kernel<<<grid, 256, 0, stream>>>(p, c, Cm, fpw, fpb,
                                             b0w0, b0b0, b0w1, b0b1,
                                             bw0, bb0, bw1, bb1,
                                             fow, fob, fold, (float*)d_out);
}